// Round 4
// baseline (252.617 us; speedup 1.0000x reference)
//
#include <hip/hip_runtime.h>

// Integrator (scaling & squaring) for vel [16,2,512,512] f32, with logdet-Jacobian.
// Intermediate disp stored INTERLEAVED [N,H,W,2]; final step de-interleaves to planar d_out.
// XCD-locality: each step's 8192 row-tasks remapped so XCD c owns images {2c,2c+1},
// rows in ascending order -> bilinear gather targets stay in that XCD's 4MB L2.
// Non-temporal dst stores keep the gather-src band L2-resident.
// ws requirement: (8388608 + 4194304) * 4 = 48 MiB.

#define NB 16
#define HH 512
#define WW 512
#define HW (HH * WW)          // 262144 = 1<<18
#define TOT (NB * HW)         // 4194304
#define EPS 0.0078125f        // 2^-7
#define DISP_ELEMS (NB * 2 * HW)   // 8388608 floats = 32 MiB

typedef float f32x2 __attribute__((ext_vector_type(2)));
typedef float f32x4 __attribute__((ext_vector_type(4)));

struct Samp {
    int i00, i01, i10, i11;
    float w00, w01, w10, w11;
};

__device__ __forceinline__ Samp make_samp(float sy, float sx) {
    float fy = floorf(sy), fx = floorf(sx);
    float wy = sy - fy, wx = sx - fx;
    int y0 = (int)fy, x0 = (int)fx;
    int y1 = y0 + 1, x1 = x0 + 1;
    bool xv0 = (unsigned)x0 < (unsigned)WW;
    bool xv1 = (unsigned)x1 < (unsigned)WW;
    bool yv0 = (unsigned)y0 < (unsigned)HH;
    bool yv1 = (unsigned)y1 < (unsigned)HH;
    int xc0 = min(max(x0, 0), WW - 1), xc1 = min(max(x1, 0), WW - 1);
    int yc0 = min(max(y0, 0), HH - 1), yc1 = min(max(y1, 0), HH - 1);
    Samp s;
    s.i00 = yc0 * WW + xc0; s.i01 = yc0 * WW + xc1;
    s.i10 = yc1 * WW + xc0; s.i11 = yc1 * WW + xc1;
    float omwx = 1.0f - wx, omwy = 1.0f - wy;
    s.w00 = (xv0 && yv0) ? omwx * omwy : 0.0f;
    s.w01 = (xv1 && yv0) ? wx * omwy   : 0.0f;
    s.w10 = (xv0 && yv1) ? omwx * wy   : 0.0f;
    s.w11 = (xv1 && yv1) ? wx * wy     : 0.0f;
    return s;
}

__device__ __forceinline__ float logdet4(float a, float b, float c, float d) {
    float tr1 = a + d;
    float xa = a * a + b * c, xb = a * b + b * d;
    float xc = c * a + d * c, xd = c * b + d * d;
    float tr2 = xa + xd;
    float ya = xa * a + xb * c, yb = xa * b + xb * d;
    float yc = xc * a + xd * c, yd = xc * b + xd * d;
    float tr3 = ya + yd;
    float tr4 = ya * a + yb * c + yc * b + yd * d;
    return EPS * tr1 - 0.5f * (EPS * EPS) * tr2
         + (1.0f / 3.0f) * (EPS * EPS * EPS) * tr3
         - 0.25f * (EPS * EPS * EPS * EPS) * tr4;
}

// init: disp0 = eps*vel (interleaved), ldjac0 = logdet series of sobel jacobian.
__global__ void __launch_bounds__(256) init_kernel(const float* __restrict__ vel,
                                                   float* __restrict__ ddst,   // interleaved [N,HW,2]
                                                   float* __restrict__ ldst) {
    int tid = blockIdx.x * 256 + threadIdx.x;
    int pix = tid * 2;
    if (pix >= TOT) return;
    int n = pix >> 18;
    int rem = pix & (HW - 1);
    int y = rem >> 9, x = rem & (WW - 1);   // x even

    const float* v0 = vel + (size_t)n * 2 * HW;
    const float* v1 = v0 + HW;

    int r0 = max(y - 1, 0) * WW;
    int r1 = y * WW;
    int r2 = min(y + 1, HH - 1) * WW;
    int c0 = max(x - 1, 0), c1 = x, c2 = x + 1, c3 = min(x + 2, WW - 1);

    float A[3][4], B[3][4];
    int rows[3] = {r0, r1, r2};
    int cols[4] = {c0, c1, c2, c3};
#pragma unroll
    for (int r = 0; r < 3; ++r)
#pragma unroll
        for (int c = 0; c < 4; ++c) {
            A[r][c] = v0[rows[r] + cols[c]];
            B[r][c] = v1[rows[r] + cols[c]];
        }

    float a0 = 0.125f * ((A[2][0] + 2.0f * A[2][1] + A[2][2]) - (A[0][0] + 2.0f * A[0][1] + A[0][2]));
    float b0 = 0.125f * ((A[0][2] + 2.0f * A[1][2] + A[2][2]) - (A[0][0] + 2.0f * A[1][0] + A[2][0]));
    float c0j = 0.125f * ((B[2][0] + 2.0f * B[2][1] + B[2][2]) - (B[0][0] + 2.0f * B[0][1] + B[0][2]));
    float d0j = 0.125f * ((B[0][2] + 2.0f * B[1][2] + B[2][2]) - (B[0][0] + 2.0f * B[1][0] + B[2][0]));

    float a1 = 0.125f * ((A[2][1] + 2.0f * A[2][2] + A[2][3]) - (A[0][1] + 2.0f * A[0][2] + A[0][3]));
    float b1 = 0.125f * ((A[0][3] + 2.0f * A[1][3] + A[2][3]) - (A[0][1] + 2.0f * A[1][1] + A[2][1]));
    float c1j = 0.125f * ((B[2][1] + 2.0f * B[2][2] + B[2][3]) - (B[0][1] + 2.0f * B[0][2] + B[0][3]));
    float d1j = 0.125f * ((B[0][3] + 2.0f * B[1][3] + B[2][3]) - (B[0][1] + 2.0f * B[1][1] + B[2][1]));

    f32x4 dd;
    dd.x = EPS * A[1][1];  dd.y = EPS * B[1][1];
    dd.z = EPS * A[1][2];  dd.w = EPS * B[1][2];
    __builtin_nontemporal_store(dd, (f32x4*)(ddst + 2 * ((size_t)n * HW + rem)));

    f32x2 ld;
    ld.x = logdet4(a0, b0, c0j, d0j);
    ld.y = logdet4(a1, b1, c1j, d1j);
    __builtin_nontemporal_store(ld, (f32x2*)(ldst + (size_t)n * HW + rem));
}

// one composition step, fused disp + ldjac update, 2 px/thread, XCD-remapped tasks.
template <bool FINAL>
__global__ void __launch_bounds__(256) step_kernel(const float* __restrict__ dsrc,  // interleaved
                                                   const float* __restrict__ lsrc,
                                                   float* __restrict__ ddst,        // interleaved (!FINAL) or planar (FINAL)
                                                   float* __restrict__ ldst) {
    // 8192 row-tasks; XCD c (= bid&7 under round-robin dispatch) gets tasks
    // [c*1024, (c+1)*1024) = images 2c,2c+1 with rows ascending.
    int bid = blockIdx.x;
    int task = ((bid & 7) << 10) | (bid >> 3);
    int tid = task * 256 + threadIdx.x;
    int pix = tid * 2;
    int n = pix >> 18;
    int rem = pix & (HW - 1);
    int y = rem >> 9, x = rem & (WW - 1);   // x even

    const float SC = 512.0f / 511.0f;

    const float* dp = dsrc + 2 * ((size_t)n * HW);
    f32x4 dd = *(const f32x4*)(dp + 2 * rem);   // (dy0,dx0, dy1,dx1)

    float nd0a, nd1a;
    {
        float sy = ((float)y + dd.x) * SC - 0.5f;
        float sx = ((float)x + dd.y) * SC - 0.5f;
        Samp s = make_samp(sy, sx);
        f32x2 g00 = *(const f32x2*)(dp + 2 * s.i00);
        f32x2 g01 = *(const f32x2*)(dp + 2 * s.i01);
        f32x2 g10 = *(const f32x2*)(dp + 2 * s.i10);
        f32x2 g11 = *(const f32x2*)(dp + 2 * s.i11);
        nd0a = dd.x + s.w00 * g00.x + s.w01 * g01.x + s.w10 * g10.x + s.w11 * g11.x;
        nd1a = dd.y + s.w00 * g00.y + s.w01 * g01.y + s.w10 * g10.y + s.w11 * g11.y;
    }
    float nd0b, nd1b;
    {
        float sy = ((float)y + dd.z) * SC - 0.5f;
        float sx = ((float)(x + 1) + dd.w) * SC - 0.5f;
        Samp s = make_samp(sy, sx);
        f32x2 g00 = *(const f32x2*)(dp + 2 * s.i00);
        f32x2 g01 = *(const f32x2*)(dp + 2 * s.i01);
        f32x2 g10 = *(const f32x2*)(dp + 2 * s.i10);
        f32x2 g11 = *(const f32x2*)(dp + 2 * s.i11);
        nd0b = dd.z + s.w00 * g00.x + s.w01 * g01.x + s.w10 * g10.x + s.w11 * g11.x;
        nd1b = dd.w + s.w00 * g00.y + s.w01 * g01.y + s.w10 * g10.y + s.w11 * g11.y;
    }

    if (FINAL) {
        float* pdy = ddst + (size_t)n * 2 * HW;
        f32x2 wy2; wy2.x = nd0a; wy2.y = nd0b;
        f32x2 wx2; wx2.x = nd1a; wx2.y = nd1b;
        __builtin_nontemporal_store(wy2, (f32x2*)(pdy + rem));
        __builtin_nontemporal_store(wx2, (f32x2*)(pdy + HW + rem));
    } else {
        f32x4 w4; w4.x = nd0a; w4.y = nd1a; w4.z = nd0b; w4.w = nd1b;
        __builtin_nontemporal_store(w4, (f32x4*)(ddst + 2 * ((size_t)n * HW + rem)));
    }

    // ldjac sampled with the NEW disp at each pixel
    const float* lp = lsrc + (size_t)n * HW;
    f32x2 l = *(const f32x2*)(lp + rem);
    f32x2 nl;
    {
        float sy = ((float)y + nd0a) * SC - 0.5f;
        float sx = ((float)x + nd1a) * SC - 0.5f;
        Samp s = make_samp(sy, sx);
        nl.x = l.x + s.w00 * lp[s.i00] + s.w01 * lp[s.i01]
                   + s.w10 * lp[s.i10] + s.w11 * lp[s.i11];
    }
    {
        float sy = ((float)y + nd0b) * SC - 0.5f;
        float sx = ((float)(x + 1) + nd1b) * SC - 0.5f;
        Samp s = make_samp(sy, sx);
        nl.y = l.y + s.w00 * lp[s.i00] + s.w01 * lp[s.i01]
                   + s.w10 * lp[s.i10] + s.w11 * lp[s.i11];
    }
    __builtin_nontemporal_store(nl, (f32x2*)(ldst + (size_t)n * HW + rem));
}

extern "C" void kernel_launch(void* const* d_in, const int* in_sizes, int n_in,
                              void* d_out, int out_size, void* d_ws, size_t ws_size,
                              hipStream_t stream) {
    const float* vel = (const float*)d_in[0];
    float* out = (float*)d_out;
    float* ws = (float*)d_ws;

    float* dispA = out;                    // d_out as raw interleaved scratch until final
    float* ldjA  = out + DISP_ELEMS;
    float* dispB = ws;
    float* ldjB  = ws + DISP_ELEMS;

    dim3 grid(TOT / 2 / 256), block(256);  // 8192 blocks

    init_kernel<<<grid, block, 0, stream>>>(vel, dispB, ldjB);

    const float* ds = dispB;
    const float* ls = ldjB;
    for (int s = 0; s < 6; ++s) {
        float* dd  = (s & 1) ? dispB : dispA;
        float* ldd = (s & 1) ? ldjB  : ldjA;
        step_kernel<false><<<grid, block, 0, stream>>>(ds, ls, dd, ldd);
        ds = dd; ls = ldd;
    }
    step_kernel<true><<<grid, block, 0, stream>>>(ds, ls, out, out + DISP_ELEMS);
}